// Round 7
// baseline (410.865 us; speedup 1.0000x reference)
//
#include <hip/hip_runtime.h>
#include <math.h>

#define N_NODES 100000
#define C_CH    64
#define E_EDGES 1200000
#define KD      32
#define HID     256
#define NPG     32
#define NGROUPS (N_NODES / NPG)     // 3125 exact
#define NCHUNK  (E_EDGES / 64)      // 18750 exact

typedef unsigned short ushort_t;
typedef short bf16x8 __attribute__((ext_vector_type(8)));
typedef short s2v    __attribute__((ext_vector_type(2)));
typedef float f32x4  __attribute__((ext_vector_type(4)));

__device__ __forceinline__ short f2bf(float f) {
    unsigned u = __builtin_bit_cast(unsigned, f);
    u = (u + 0x7fffu + ((u >> 16) & 1u)) >> 16;   // RNE
    return (short)u;
}
__device__ __forceinline__ float bf2f(ushort_t u) {
    return __builtin_bit_cast(float, (unsigned)u << 16);
}
__device__ __forceinline__ float bf2f_lo(unsigned p) {
    return __builtin_bit_cast(float, p << 16);
}
__device__ __forceinline__ float bf2f_hi(unsigned p) {
    return __builtin_bit_cast(float, p & 0xffff0000u);
}

// packed bf16x2 atomic add (HW global_atomic_pk_add_bf16 on gfx950)
__device__ __forceinline__ void pk_atomic_bf16(void* p, float m0, float m1) {
    s2v v; v[0] = f2bf(m0); v[1] = f2bf(m1);
#if __has_builtin(__builtin_amdgcn_global_atomic_fadd_v2bf16)
    typedef __attribute__((address_space(1))) s2v* gpt;
    __builtin_amdgcn_global_atomic_fadd_v2bf16((gpt)(unsigned long long)p, v);
#else
    unsigned* up = (unsigned*)p;
    unsigned old = __hip_atomic_load(up, __ATOMIC_RELAXED, __HIP_MEMORY_SCOPE_AGENT);
    unsigned assumed;
    do {
        assumed = old;
        float a0 = bf2f_lo(assumed) + m0;
        float a1 = bf2f_hi(assumed) + m1;
        unsigned nv = (unsigned)(ushort_t)f2bf(a0)
                    | ((unsigned)(ushort_t)f2bf(a1) << 16);
        old = atomicCAS(up, assumed, nv);
    } while (old != assumed);
#endif
}

// ---------------------------------------------------------------------------
// xcast: x fp32 -> bf16 (streaming) AND zero x1b (replaces memset dispatch).
// Verified R4: FETCH 219.6 -> 148.9 MB. Numerically safe: message path is
// scaled by layer_scale=1e-6; fp32 residual x is read by node_kernel.
// ---------------------------------------------------------------------------
__global__ __launch_bounds__(256) void xcast_kernel(
    const float* __restrict__ x, ushort_t* __restrict__ xb,
    ushort_t* __restrict__ x1b)
{
    const int stride = gridDim.x * 256;
    const uint2 z = make_uint2(0u, 0u);
    for (int k = blockIdx.x * 256 + threadIdx.x; k < N_NODES * C_CH / 4;
         k += stride) {
        const float4 v = *(const float4*)(x + 4 * (size_t)k);
        s2v a, b;
        a[0] = f2bf(v.x); a[1] = f2bf(v.y);
        b[0] = f2bf(v.z); b[1] = f2bf(v.w);
        uint2 o;
        o.x = __builtin_bit_cast(unsigned, a);
        o.y = __builtin_bit_cast(unsigned, b);
        *(uint2*)(xb + 4 * (size_t)k) = o;
        *(uint2*)(x1b + 4 * (size_t)k) = z;
    }
}

// ---------------------------------------------------------------------------
// K1 v6: barrier-free + 2-deep software-pipelined message passing.
// R6 diagnosis: all per-chunk loads and atomics share the vmcnt FIFO; any
// load-consume after atomic-issue forces retiring ALL older atomics
// (~600-900cy coherence round trip) -> every wave drained its atomics every
// chunk (explains R1/R4/R6 invariance at ~140us with all pipes <30%).
// Fix: issue-order pipeline so loads for chunk c are issued BEFORE atomics
// of chunk c-1's successor window:
//   steady state per iter: MFMA(c)+LDS -> issue kb(c+1) -> issue x(c+1),
//   dst-sloads(c) -> consume x(c) [oldest in FIFO: atomics(c-1) were issued
//   AFTER x(c)... order last iter: x(c) then atomics(c-1)? No: x(c) issued
//   in iter c-1's prefetch, atomics(c-1) issued later in that iter, so x(c)
//   is OLDER and retires first -> counted vmcnt never waits on atomics].
// LDS stays short-typed + asm fences (R6-proven TBAA-safe, passes).
// ---------------------------------------------------------------------------
__global__ __launch_bounds__(256) void edge_kernel(
    const ushort_t* __restrict__ xb, const float* __restrict__ kb,
    const int* __restrict__ ei, const float* __restrict__ kW,
    ushort_t* __restrict__ x1b)
{
    __shared__ short sbuf[4][16][68];   // 8.7 KB: [wave][edge-row][short col]

    const int t    = threadIdx.x;
    const int lane = t & 63;
    const int w    = __builtin_amdgcn_readfirstlane(t >> 6);
    const int nlo  = lane & 15;
    const int quad = lane >> 4;
    const int cp   = lane & 31;       // channel-pair index
    const int hf   = lane >> 5;       // half-wave: edge j vs j+8

    // B fragments: B[k][n] = kW[16t+n][k], lane k = quad*8+j
    bf16x8 bW[4];
    #pragma unroll
    for (int tt = 0; tt < 4; ++tt) {
        const float* p = kW + (size_t)(16 * tt + nlo) * KD + quad * 8;
        #pragma unroll
        for (int q = 0; q < 8; ++q) bW[tt][q] = f2bf(p[q]);
    }

    short* srow = &sbuf[w][0][0];     // row stride 68 shorts

    const int stride = gridDim.x;
    int c = blockIdx.x;
    if (c >= NCHUNK) return;

    // ---- prologue: prefetch chunk c (kb raw + x-gathers) ----
    float4 kraw0, kraw1;
    unsigned xpf[8];
    {
        const int e0 = c * 64 + w * 16;
        const float* ap = kb + (size_t)(e0 + nlo) * KD + quad * 8;
        kraw0 = *(const float4*)(ap);
        kraw1 = *(const float4*)(ap + 4);
        #pragma unroll
        for (int j = 0; j < 8; ++j) {
            const int sA = ei[e0 + j], sB = ei[e0 + j + 8];
            const int src = hf ? sB : sA;
            xpf[j] = *(const unsigned*)(xb + (size_t)src * C_CH + 2 * cp);
        }
    }

    for (;;) {
        const int cn = c + stride;
        const bool has_next = (cn < NCHUNK);
        const int e0 = c * 64 + w * 16;

        // ---- MFMA coef for chunk c (kb raw regs -> bf16 frags) ----
        bf16x8 af;
        af[0] = f2bf(kraw0.x); af[1] = f2bf(kraw0.y);
        af[2] = f2bf(kraw0.z); af[3] = f2bf(kraw0.w);
        af[4] = f2bf(kraw1.x); af[5] = f2bf(kraw1.y);
        af[6] = f2bf(kraw1.z); af[7] = f2bf(kraw1.w);
        #pragma unroll
        for (int tt = 0; tt < 4; ++tt) {
            f32x4 d = {0.f, 0.f, 0.f, 0.f};
            d = __builtin_amdgcn_mfma_f32_16x16x32_bf16(af, bW[tt], d, 0, 0, 0);
            #pragma unroll
            for (int r = 0; r < 4; ++r)
                srow[(quad * 4 + r) * 68 + 16 * tt + nlo] = f2bf(d[r]);
        }

        // ---- prefetch chunk c+1 (issued BEFORE this chunk's atomics) ----
        float4 nk0, nk1;
        unsigned nxpf[8];
        if (has_next) {
            const int e1 = cn * 64 + w * 16;
            const float* np = kb + (size_t)(e1 + nlo) * KD + quad * 8;
            nk0 = *(const float4*)(np);
            nk1 = *(const float4*)(np + 4);
            #pragma unroll
            for (int j = 0; j < 8; ++j) {
                const int sA = ei[e1 + j], sB = ei[e1 + j + 8];
                const int src = hf ? sB : sA;
                nxpf[j] = *(const unsigned*)(xb + (size_t)src * C_CH + 2 * cp);
            }
        }

        // dst indices for chunk c (loaded pre-fence; values live in regs)
        int dstv[8];
        #pragma unroll
        for (int j = 0; j < 8; ++j) {
            const int dA = ei[E_EDGES + e0 + j], dB = ei[E_EDGES + e0 + j + 8];
            dstv[j] = hf ? dB : dA;
        }

        asm volatile("" ::: "memory");   // phase fence: order ds_write->ds_read

        // ---- scatter chunk c: prefetched x + LDS coef -> pk atomics ----
        #pragma unroll
        for (int j = 0; j < 8; ++j) {
            const int ro  = (j + hf * 8) * 68 + 2 * cp;
            const unsigned lo = (ushort_t)srow[ro];
            const unsigned hi = (ushort_t)srow[ro + 1];
            const unsigned cf = lo | (hi << 16);
            const unsigned xv = xpf[j];
            pk_atomic_bf16(x1b + (size_t)dstv[j] * C_CH + 2 * cp,
                           bf2f_lo(xv) * bf2f_lo(cf),
                           bf2f_hi(xv) * bf2f_hi(cf));
        }

        asm volatile("" ::: "memory");   // phase fence: order reads->next writes

        if (!has_next) break;
        kraw0 = nk0; kraw1 = nk1;
        #pragma unroll
        for (int j = 0; j < 8; ++j) xpf[j] = nxpf[j];
        c = cn;
    }
}

// ---------------------------------------------------------------------------
// K2: conv_bias + LN (fp32) -> bf16 MFMA GEMM1 -> exact GELU -> bf16 MFMA
// GEMM2 -> layerscale + residual. x1 is bf16. (unchanged)
// ---------------------------------------------------------------------------
__global__ __launch_bounds__(256, 2) void node_kernel(
    const float* __restrict__ x,  const ushort_t* __restrict__ x1b,
    const float* __restrict__ conv_bias, const float* __restrict__ gamma,
    const float* __restrict__ beta, const float* __restrict__ W1,
    const float* __restrict__ b1, const float* __restrict__ W2,
    const float* __restrict__ b2, const float* __restrict__ ls,
    float* __restrict__ out)
{
    __shared__ short lnb[NPG][C_CH + 8];
    __shared__ short gb[NPG][HID + 8];

    const int t    = threadIdx.x;
    const int lane = t & 63;
    const int w    = t >> 6;
    const int nlo  = lane & 15;
    const int quad = lane >> 4;

    bf16x8 b1f[4][2];
    float  b1v[4];
    #pragma unroll
    for (int t1 = 0; t1 < 4; ++t1) {
        const int j = (4 * w + t1) * 16 + nlo;
        b1v[t1] = b1[j];
        #pragma unroll
        for (int s = 0; s < 2; ++s) {
            const float* p = W1 + (size_t)j * C_CH + s * 32 + quad * 8;
            #pragma unroll
            for (int q = 0; q < 8; ++q) b1f[t1][s][q] = f2bf(p[q]);
        }
    }
    bf16x8 b2f[8];
    #pragma unroll
    for (int s2 = 0; s2 < 8; ++s2) {
        const float* p = W2 + (size_t)(w * 16 + nlo) * HID + s2 * 32 + quad * 8;
        #pragma unroll
        for (int q = 0; q < 8; ++q) b2f[s2][q] = f2bf(p[q]);
    }
    const float biasc  = conv_bias[lane];
    const float gammac = gamma[lane];
    const float betac  = beta[lane];
    const float b2v    = b2[w * 16 + nlo];
    const float lsv    = ls[w * 16 + nlo];

    for (int g = blockIdx.x; g < NGROUPS; g += gridDim.x) {
        const int base = g * NPG;

        #pragma unroll
        for (int q = 0; q < 8; ++q) {
            const int loc = w * 8 + q;
            float v = bf2f(x1b[(size_t)(base + loc) * C_CH + lane]) + biasc;
            float s = v, ss = v * v;
            #pragma unroll
            for (int o = 32; o > 0; o >>= 1) {
                s  += __shfl_xor(s,  o, 64);
                ss += __shfl_xor(ss, o, 64);
            }
            float mu   = s * (1.f / 64.f);
            float rstd = rsqrtf(ss * (1.f / 64.f) - mu * mu + 1e-5f);
            lnb[loc][lane] = f2bf((v - mu) * rstd * gammac + betac);
        }
        __syncthreads();

        #pragma unroll
        for (int mt = 0; mt < 2; ++mt) {
            bf16x8 a1[2];
            #pragma unroll
            for (int s = 0; s < 2; ++s)
                a1[s] = *(const bf16x8*)&lnb[mt * 16 + nlo][s * 32 + quad * 8];
            #pragma unroll
            for (int t1 = 0; t1 < 4; ++t1) {
                f32x4 c = {0.f, 0.f, 0.f, 0.f};
                c = __builtin_amdgcn_mfma_f32_16x16x32_bf16(a1[0], b1f[t1][0], c, 0, 0, 0);
                c = __builtin_amdgcn_mfma_f32_16x16x32_bf16(a1[1], b1f[t1][1], c, 0, 0, 0);
                #pragma unroll
                for (int r = 0; r < 4; ++r) {
                    float h = c[r] + b1v[t1];
                    h = 0.5f * h * (1.f + erff(h * 0.70710678f));
                    gb[mt * 16 + quad * 4 + r][(4 * w + t1) * 16 + nlo] = f2bf(h);
                }
            }
        }
        __syncthreads();

        #pragma unroll
        for (int mt = 0; mt < 2; ++mt) {
            f32x4 c2 = {0.f, 0.f, 0.f, 0.f};
            #pragma unroll
            for (int s2 = 0; s2 < 8; ++s2) {
                bf16x8 a2 = *(const bf16x8*)&gb[mt * 16 + nlo][s2 * 32 + quad * 8];
                c2 = __builtin_amdgcn_mfma_f32_16x16x32_bf16(a2, b2f[s2], c2, 0, 0, 0);
            }
            #pragma unroll
            for (int r = 0; r < 4; ++r) {
                const int node = base + mt * 16 + quad * 4 + r;
                const int cch  = w * 16 + nlo;
                float h2 = c2[r] + b2v;
                out[(size_t)node * C_CH + cch] =
                    lsv * h2 + x[(size_t)node * C_CH + cch];
            }
        }
        __syncthreads();
    }
}

extern "C" void kernel_launch(void* const* d_in, const int* in_sizes, int n_in,
                              void* d_out, int out_size, void* d_ws, size_t ws_size,
                              hipStream_t stream) {
    const float* x   = (const float*)d_in[0];
    const float* kb  = (const float*)d_in[1];
    // d_in[2] = fiber_kernel_basis (unused)
    const int*   ei  = (const int*)d_in[3];
    const float* kW  = (const float*)d_in[4];
    const float* cb  = (const float*)d_in[5];
    const float* gm  = (const float*)d_in[6];
    const float* bt  = (const float*)d_in[7];
    const float* W1  = (const float*)d_in[8];
    const float* b1  = (const float*)d_in[9];
    const float* W2  = (const float*)d_in[10];
    const float* b2  = (const float*)d_in[11];
    const float* ls  = (const float*)d_in[12];
    float* out = (float*)d_out;

    // workspace: x1b bf16 accumulator (12.8 MB) + xb bf16 copy of x (12.8 MB)
    ushort_t* x1b = (ushort_t*)d_ws;
    ushort_t* xb  = (ushort_t*)d_ws + (size_t)N_NODES * C_CH;

    xcast_kernel<<<1024, 256, 0, stream>>>(x, xb, x1b);
    edge_kernel<<<2048, 256, 0, stream>>>(xb, kb, ei, kW, x1b);
    node_kernel<<<2048, 256, 0, stream>>>(x, x1b, cb, gm, bt, W1, b1, W2, b2, ls, out);
}